// Round 3
// baseline (560.502 us; speedup 1.0000x reference)
//
#include <hip/hip_runtime.h>
#include <stdint.h>

// Problem: 3D correlation, x1/x2 (1,32,48,48,48) fp32 inputs, D_MAX=4 -> 9^3=729 offsets.
// out[(i*9+j)*9+k][h][w][d] = (1/32) * sum_c x1[c,h,w,d] * x2[c, h+i-4, w+j-4, d+k-4]
// (zero outside bounds), output fp32 (reference returns float32), (1,729,48,48,48).
//
// Dtype evidence: r1 (inputs as bf16) -> NaN: fp32 bits read as bf16 give Inf/NaN at
// ~1/256 rate => inputs are fp32 buffers. r2 (output as bf16) -> absmax 1.527 which
// matches max|ref[2n]-ref[2n+1]| for fp32 reads of packed bf16 pairs => output is fp32.

#define CCH_TOT 32
#define HH 48
#define WW 48
#define DD 48
#define PAD 4
#define OD 9           // offsets per axis
#define WT 4           // w positions per block
#define PP 8           // d positions per thread
#define NDG 6          // d-groups (48 / 8)
#define CCH 8          // channels per chunk
#define NCHUNK 4       // 32 / 8
#define X2ROW 56       // staged x2 d-extent (-4..51)
#define X2W 12         // staged x2 w-extent (w0-4 .. w0+7)
#define NACT 216       // active compute threads: WT * OD * NDG

__global__ __launch_bounds__(256, 2) void corr_kernel(
    const float* __restrict__ x1,
    const float* __restrict__ x2,
    float* __restrict__ out) {

  __shared__ __attribute__((aligned(16))) float s_x2[CCH][X2W * X2ROW]; // 8*672 f32 = 21.5 KB
  __shared__ __attribute__((aligned(16))) float s_x1[CCH][WT * DD];     // 8*192 f32 = 6 KB

  const int wt = blockIdx.x;   // 0..11
  const int h  = blockIdx.y;   // 0..47
  const int i  = blockIdx.z;   // 0..8
  const int w0 = wt * WT;
  const int r  = h + i - PAD;  // x2 H row needed by this block (may be out of range)
  const int t  = threadIdx.x;

  // compute-thread mapping: t = dg + 6*j + 54*wl   (dg fastest -> consecutive d on stores)
  const bool active = (t < NACT);
  int wl = 0, j = 0, dg = 0;
  if (active) {
    wl = t / (OD * NDG);
    int rem = t - wl * (OD * NDG);
    j = rem / NDG;
    dg = rem - j * NDG;
  }
  const int d0 = dg * PP;

  float acc[OD][PP];
#pragma unroll
  for (int k = 0; k < OD; ++k)
#pragma unroll
    for (int p = 0; p < PP; ++p) acc[k][p] = 0.0f;

  const bool row_ok = (r >= 0) & (r < HH);

  for (int ch = 0; ch < NCHUNK; ++ch) {
    const int cbase = ch * CCH;
    __syncthreads();  // protect previous iteration's LDS reads

    // ---- stage x2 chunk: CCH x 12(w) x 56(d), zero-padded out of bounds ----
    for (int idx = t; idx < CCH * X2W * X2ROW; idx += 256) {
      int c    = idx / (X2W * X2ROW);
      int remi = idx - c * (X2W * X2ROW);
      int wx   = remi / X2ROW;
      int dx   = remi - wx * X2ROW;
      int wg   = w0 + wx - PAD;
      int dgl  = dx - PAD;
      float v = 0.0f;
      if (row_ok && (unsigned)wg < (unsigned)WW && (unsigned)dgl < (unsigned)DD) {
        size_t gidx = (((size_t)(cbase + c) * HH + r) * WW + wg) * DD + dgl;
        v = x2[gidx];
      }
      s_x2[c][remi] = v;
    }
    // ---- stage x1 chunk: CCH x WT x 48 (always in bounds) ----
    for (int idx = t; idx < CCH * WT * DD; idx += 256) {
      int c    = idx / (WT * DD);
      int remi = idx - c * (WT * DD);
      int wx   = remi / DD;
      int dx   = remi - wx * DD;
      size_t gidx = (((size_t)(cbase + c) * HH + h) * WW + (w0 + wx)) * DD + dx;
      s_x1[c][remi] = x1[gidx];
    }
    __syncthreads();

    if (active) {
      for (int c = 0; c < CCH; ++c) {
        float xv[PP];
        const float* px1 = &s_x1[c][wl * DD + d0];
#pragma unroll
        for (int p = 0; p < PP; ++p) xv[p] = px1[p];
        // window covers d' = d0-4 .. d0+11 (stored index d0 .. d0+15)
        float win[PP + 8];
        const float* px2 = &s_x2[c][(wl + j) * X2ROW + d0];
#pragma unroll
        for (int q = 0; q < PP + 8; ++q) win[q] = px2[q];
#pragma unroll
        for (int k = 0; k < OD; ++k)
#pragma unroll
          for (int p = 0; p < PP; ++p)
            acc[k][p] = fmaf(xv[p], win[p + k], acc[k][p]);
      }
    }
  }

  if (active) {
    const float inv = 1.0f / 32.0f;
    const size_t spat = ((size_t)h * WW + (w0 + wl)) * DD + d0;
#pragma unroll
    for (int k = 0; k < OD; ++k) {
      const int o = (i * OD + j) * OD + k;
      float4 lo = make_float4(acc[k][0] * inv, acc[k][1] * inv,
                              acc[k][2] * inv, acc[k][3] * inv);
      float4 hi = make_float4(acc[k][4] * inv, acc[k][5] * inv,
                              acc[k][6] * inv, acc[k][7] * inv);
      float* dst = out + (size_t)o * (HH * WW * DD) + spat;
      *reinterpret_cast<float4*>(dst)     = lo;
      *reinterpret_cast<float4*>(dst + 4) = hi;
    }
  }
}

extern "C" void kernel_launch(void* const* d_in, const int* in_sizes, int n_in,
                              void* d_out, int out_size, void* d_ws, size_t ws_size,
                              hipStream_t stream) {
  const float* x1 = (const float*)d_in[0];
  const float* x2 = (const float*)d_in[1];
  float* out = (float*)d_out;
  dim3 grid(WW / WT, HH, OD);  // (12, 48, 9)
  corr_kernel<<<grid, 256, 0, stream>>>(x1, x2, out);
}

// Round 4
// 394.348 us; speedup vs baseline: 1.4213x; 1.4213x over previous
//
#include <hip/hip_runtime.h>
#include <stdint.h>

// 3D correlation: x1/x2 (1,32,48,48,48) fp32, D_MAX=4 -> 729 offsets, out fp32 (1,729,48,48,48).
// out[(i*9+j)*9+k][h][w][d] = (1/32) * sum_c x1[c,h,w,d] * x2[c, h+i-4, w+j-4, d+k-4]
//
// R4 changes vs R3 (305 us): staging was ~half the VALU work (27 guarded scalar loads
// x 3 magic-divs each per thread per chunk). Now: float4 units, LDS slot = unit_idx*16B
// (layout is linear in idx -> zero LDS index math; d-pads are whole zero float4s),
// loads batched into regs BEFORE the barrier (latency overlaps other waves' compute),
// stores after. ~4x fewer staging instructions.

#define HH 48
#define WW 48
#define DD 48
#define PAD 4
#define OD 9
#define WT 4            // w positions per block
#define PP 8            // d positions per thread
#define NDG 6           // 48/8
#define CCH 8           // channels per chunk
#define NCHUNK 4
#define X2ROW 56        // staged x2 d extent (-4..51), 14 float4
#define X2W 12          // staged x2 w extent (w0-4..w0+7)
#define NACT 216        // WT*OD*NDG
#define X2_UNITS 1344   // CCH * X2W * 14
#define X1_UNITS 384    // CCH * WT * 12

__global__ __launch_bounds__(256, 2) void corr_kernel(
    const float* __restrict__ x1,
    const float* __restrict__ x2,
    float* __restrict__ out) {

  __shared__ __attribute__((aligned(16))) float s_x2[CCH * X2W * X2ROW]; // 21.5 KB
  __shared__ __attribute__((aligned(16))) float s_x1[CCH * WT * DD];     // 6 KB

  const int wt = blockIdx.x;   // 0..11
  const int h  = blockIdx.y;   // 0..47
  const int i  = blockIdx.z;   // 0..8
  const int w0 = wt * WT;
  const int r  = h + i - PAD;
  const int t  = threadIdx.x;
  const bool row_ok = (r >= 0) & (r < HH);

  // compute-thread mapping: t = dg + 6*j + 54*wl (dg fastest -> contiguous d stores)
  const bool active = (t < NACT);
  int wl = 0, j = 0, dg = 0;
  if (active) {
    wl = t / (OD * NDG);
    int rem = t - wl * (OD * NDG);
    j = rem / NDG;
    dg = rem - j * NDG;
  }
  const int d0 = dg * PP;

  float acc[OD][PP];
#pragma unroll
  for (int k = 0; k < OD; ++k)
#pragma unroll
    for (int p = 0; p < PP; ++p) acc[k][p] = 0.0f;

  // per-block invariant pieces of the x2 global address (row r fixed)
  const int rbase = r * (WW * DD);          // may be garbage if !row_ok; guarded

  for (int ch = 0; ch < NCHUNK; ++ch) {
    const int cbase = ch * CCH;

    // ---------- issue all global loads for this chunk into registers ----------
    // x2 units: idx -> (c = idx/168, w = (idx%168)/14, pos = idx%14)
    //   pos==0 / pos==13 are the d-halo pads (pure zeros); pos 1..12 -> d = (pos-1)*4
    float4 v2[6];
#pragma unroll
    for (int u = 0; u < 6; ++u) {
      const int idx = t + u * 256;
      const bool have = (u < 5) || (idx < X2_UNITS);
      const int c   = idx / 168;
      const int rm  = idx - c * 168;
      const int w   = rm / 14;
      const int pos = rm - w * 14;
      const int wg  = w0 + w - PAD;
      float4 val = make_float4(0.f, 0.f, 0.f, 0.f);
      const bool in = have & row_ok & ((unsigned)wg < (unsigned)WW) &
                      ((unsigned)(pos - 1) < 12u);
      if (in) {
        const size_t g = (size_t)(cbase + c) * (HH * WW * DD) + rbase +
                         wg * DD + (pos - 1) * 4;
        val = *reinterpret_cast<const float4*>(x2 + g);
      }
      v2[u] = val;
    }
    // x1 units: idx -> (c = idx/48, lin = idx%48); (w,d) contiguous in global memory
    float4 v1[2];
#pragma unroll
    for (int u = 0; u < 2; ++u) {
      const int idx = t + u * 256;
      const bool have = (u < 1) || (idx < X1_UNITS);
      float4 val = make_float4(0.f, 0.f, 0.f, 0.f);
      if (have) {
        const int c   = idx / 48;
        const int lin = idx - c * 48;
        const size_t g = (size_t)(cbase + c) * (HH * WW * DD) +
                         (size_t)h * (WW * DD) + w0 * DD + lin * 4;
        val = *reinterpret_cast<const float4*>(x1 + g);
      }
      v1[u] = val;
    }

    __syncthreads();  // all waves done reading previous chunk's LDS

    // ---------- store to LDS: slot is LINEAR in unit idx (no index math) ----------
#pragma unroll
    for (int u = 0; u < 6; ++u) {
      const int idx = t + u * 256;
      if ((u < 5) || (idx < X2_UNITS))
        *reinterpret_cast<float4*>(s_x2 + idx * 4) = v2[u];
    }
#pragma unroll
    for (int u = 0; u < 2; ++u) {
      const int idx = t + u * 256;
      if ((u < 1) || (idx < X1_UNITS))
        *reinterpret_cast<float4*>(s_x1 + idx * 4) = v1[u];
    }
    __syncthreads();

    // ---------- compute ----------
    if (active) {
      for (int c = 0; c < CCH; ++c) {
        float xv[PP];
        const float* px1 = &s_x1[c * (WT * DD) + wl * DD + d0];
#pragma unroll
        for (int p = 0; p < PP; ++p) xv[p] = px1[p];
        float win[PP + 8];
        const float* px2 = &s_x2[c * (X2W * X2ROW) + (wl + j) * X2ROW + d0];
#pragma unroll
        for (int q = 0; q < PP + 8; ++q) win[q] = px2[q];
#pragma unroll
        for (int k = 0; k < OD; ++k)
#pragma unroll
          for (int p = 0; p < PP; ++p)
            acc[k][p] = fmaf(xv[p], win[p + k], acc[k][p]);
      }
    }
  }

  if (active) {
    const float inv = 1.0f / 32.0f;
    const size_t spat = ((size_t)h * WW + (w0 + wl)) * DD + d0;
#pragma unroll
    for (int k = 0; k < OD; ++k) {
      const int o = (i * OD + j) * OD + k;
      float4 lo = make_float4(acc[k][0] * inv, acc[k][1] * inv,
                              acc[k][2] * inv, acc[k][3] * inv);
      float4 hi = make_float4(acc[k][4] * inv, acc[k][5] * inv,
                              acc[k][6] * inv, acc[k][7] * inv);
      float* dst = out + (size_t)o * (HH * WW * DD) + spat;
      *reinterpret_cast<float4*>(dst)     = lo;
      *reinterpret_cast<float4*>(dst + 4) = hi;
    }
  }
}

extern "C" void kernel_launch(void* const* d_in, const int* in_sizes, int n_in,
                              void* d_out, int out_size, void* d_ws, size_t ws_size,
                              hipStream_t stream) {
  const float* x1 = (const float*)d_in[0];
  const float* x2 = (const float*)d_in[1];
  float* out = (float*)d_out;
  dim3 grid(WW / WT, HH, OD);  // (12, 48, 9)
  corr_kernel<<<grid, 256, 0, stream>>>(x1, x2, out);
}